// Round 1
// baseline (859.314 us; speedup 1.0000x reference)
//
#include <hip/hip_runtime.h>

typedef __attribute__((ext_vector_type(8))) short short8;
typedef __attribute__((ext_vector_type(4))) float f32x4;

#define S_LEN 2048
#define BATCH 4
#define DM 1024
#define DI 2048
#define DS 64
#define DTR 64
#define XPW 192   // dt_rank + 2*d_state

__device__ __forceinline__ unsigned short f2bf(float f){
  unsigned u = __builtin_bit_cast(unsigned, f);
  u += 0x7fffu + ((u >> 16) & 1u);
  return (unsigned short)(u >> 16);
}
__device__ __forceinline__ float bf2f(unsigned short h){
  unsigned u = ((unsigned)h) << 16;
  return __builtin_bit_cast(float, u);
}
__device__ __forceinline__ void gload16(const void* g, void* l){
  __builtin_amdgcn_global_load_lds((const __attribute__((address_space(1))) void*)g,
                                   (__attribute__((address_space(3))) void*)l, 16, 0, 0);
}
__device__ __forceinline__ float siluf_(float v){ return v / (1.f + __expf(-v)); }

// ---------------- f32 -> bf16 convert ----------------
__global__ __launch_bounds__(256) void cvt_bf16_k(const float* __restrict__ in,
                                                  unsigned short* __restrict__ out, int n){
  int i = (blockIdx.x * 256 + threadIdx.x) * 4;
  if (i >= n) return;
  float4 v = *(const float4*)(in + i);
  ushort4 o;
  o.x = f2bf(v.x); o.y = f2bf(v.y); o.z = f2bf(v.z); o.w = f2bf(v.w);
  *(ushort4*)(out + i) = o;
}

// ---------------- bf16 MFMA GEMM, C = A[M,K] * B[N,K]^T + bias ----------------
// 128x128 tile, BK=32, 4 waves (2x2), 16x16x32 MFMA, global_load_lds width=16.
// EPI 0: v+bias; EPI 1: softplus(v+2*bias); EPI 2: v+bias, silu when col>=nsilu.
template<int EPI, bool WB16>
__global__ __launch_bounds__(256)
void gemm_bt(const unsigned short* __restrict__ A, const unsigned short* __restrict__ B,
             float* __restrict__ C, unsigned short* __restrict__ Cb,
             const float* __restrict__ bias,
             int N, int K, int lda, int ldb, int ldc, int nsilu)
{
  __shared__ unsigned short As[128 * 32];
  __shared__ unsigned short Bs[128 * 32];
  const int tid  = threadIdx.x;
  const int lane = tid & 63;
  const int wid  = tid >> 6;
  const int bm = blockIdx.x, bn = blockIdx.y;
  const int r0 = tid >> 2;           // 0..63
  const int c0 = (tid & 3) * 8;      // 0,8,16,24
  int brow0 = bn * 128 + r0;        if (brow0 > N - 1) brow0 = N - 1;
  int brow1 = bn * 128 + 64 + r0;   if (brow1 > N - 1) brow1 = N - 1;
  const unsigned short* pa0 = A + (size_t)(bm * 128 + r0) * lda + c0;
  const unsigned short* pa1 = A + (size_t)(bm * 128 + 64 + r0) * lda + c0;
  const unsigned short* pb0 = B + (size_t)brow0 * ldb + c0;
  const unsigned short* pb1 = B + (size_t)brow1 * ldb + c0;
  f32x4 acc[4][4] = {};
  const int fr = lane & 15, fq = lane >> 4;
  const int wm = (wid >> 1) * 64, wn = (wid & 1) * 64;
  const int aoff0 = (wm + fr) * 32 + fq * 8;
  const int boff0 = (wn + fr) * 32 + fq * 8;
  for (int k0 = 0; k0 < K; k0 += 32) {
    __syncthreads();                       // prev-iter LDS reads done
    gload16(pa0 + k0, &As[tid * 8]);
    gload16(pa1 + k0, &As[2048 + tid * 8]);
    gload16(pb0 + k0, &Bs[tid * 8]);
    gload16(pb1 + k0, &Bs[2048 + tid * 8]);
    __syncthreads();                       // drains vmcnt(0): LDS ready
    short8 av[4], bv[4];
#pragma unroll
    for (int i = 0; i < 4; i++) av[i] = *(const short8*)&As[aoff0 + i * 16 * 32];
#pragma unroll
    for (int i = 0; i < 4; i++) bv[i] = *(const short8*)&Bs[boff0 + i * 16 * 32];
#pragma unroll
    for (int i = 0; i < 4; i++)
#pragma unroll
      for (int j = 0; j < 4; j++)
        acc[i][j] = __builtin_amdgcn_mfma_f32_16x16x32_bf16(av[i], bv[j], acc[i][j], 0, 0, 0);
  }
#pragma unroll
  for (int i = 0; i < 4; i++) {
#pragma unroll
    for (int j = 0; j < 4; j++) {
      int gc = bn * 128 + wn + j * 16 + fr;
      if (gc >= N) continue;
      float bb = bias[gc];
#pragma unroll
      for (int e = 0; e < 4; e++) {
        int gr = bm * 128 + wm + i * 16 + fq * 4 + e;
        float v = acc[i][j][e];
        if (EPI == 0)      { v += bb; }
        else if (EPI == 1) { v += 2.f * bb; v = fmaxf(v, 0.f) + log1pf(__expf(-fabsf(v))); }
        else               { v += bb; if (gc >= nsilu) v = siluf_(v); }
        C[(size_t)gr * ldc + gc] = v;
        if (WB16) Cb[(size_t)gr * ldc + gc] = f2bf(v);
      }
    }
  }
}

// ---------------- causal depthwise conv (K=4) + silu, bf16 out ----------------
__global__ __launch_bounds__(256) void conv_k(const float* __restrict__ xz,
                                              const float* __restrict__ cw,
                                              const float* __restrict__ cb,
                                              unsigned short* __restrict__ xconvb)
{
  int idx = blockIdx.x * 256 + threadIdx.x;   // over 8192*2048
  int d = idx & (DI - 1);
  int r = idx >> 11;                           // r = t*B + b
  const float* p = xz + (size_t)r * 4096 + d;  // x_inner cols 0..2047
  float s = cb[d];
  float w0 = cw[d * 4], w1 = cw[d * 4 + 1], w2 = cw[d * 4 + 2], w3 = cw[d * 4 + 3];
  s += w3 * p[0];
  if (r >= 4)  s += w2 * p[-4  * 4096];
  if (r >= 8)  s += w1 * p[-8  * 4096];
  if (r >= 12) s += w0 * p[-12 * 4096];
  s = siluf_(s);
  xconvb[idx] = f2bf(s);
}

// ---------------- selective scan: one wave per (b,d), lane = n ----------------
__global__ __launch_bounds__(256) void scan_k(const float* __restrict__ xz,     // dt cols 0..2047, gate cols 2048..
                                              const unsigned short* __restrict__ xconvb,
                                              const float* __restrict__ xp,     // [8192][192]
                                              const float* __restrict__ A_log,
                                              const float* __restrict__ Dv,
                                              const float* __restrict__ state_in,
                                              float* __restrict__ accbuf,
                                              float* __restrict__ state_out)
{
  const int tid  = threadIdx.x;
  const int lane = tid & 63;
  const int gw = blockIdx.x * 4 + (tid >> 6);  // 0..8191
  const int b = gw >> 11;
  const int d = gw & (DI - 1);
  const int du = __builtin_amdgcn_readfirstlane(d);
  const int bu = __builtin_amdgcn_readfirstlane(b);
  const float LOG2E = 1.442695040888963f;
  float a2 = -exp2f(A_log[(size_t)du * DS + lane] * LOG2E) * LOG2E;  // A*log2e
  float state = state_in[((size_t)(bu * DI + du)) * DS + lane];
  int off_dt = bu * 4096 + du;          // +16384/t
  int off_g  = off_dt + 2048;
  int off_x  = bu * 2048 + du;          // +8192/t
  int off_bc = bu * XPW + DTR;          // +768/t
  float acc = 0.f, sx = 0.f;
  float dt0 = xz[off_dt], g0 = xz[off_g], x0 = bf2f(xconvb[off_x]);
  float B0 = xp[off_bc + lane], C0 = xp[off_bc + 64 + lane];
  off_dt += 16384; off_g += 16384; off_x += 8192; off_bc += 768;
  float dt1 = xz[off_dt], g1 = xz[off_g], x1 = bf2f(xconvb[off_x]);
  float B1 = xp[off_bc + lane], C1 = xp[off_bc + 64 + lane];
  // note: final 2 prefetches run past the arrays into adjacent ws scratch (safe, discarded)
  for (int t = 0; t < S_LEN; t += 2) {
    off_dt += 16384; off_g += 16384; off_x += 8192; off_bc += 768;
    float pdt = xz[off_dt], pg = xz[off_g], px = bf2f(xconvb[off_x]);
    float pB = xp[off_bc + lane], pC = xp[off_bc + 64 + lane];
    float dA = exp2f(dt0 * a2);
    state = fmaf(state, dA, (dt0 * x0) * B0);
    acc = fmaf(state * C0, g0, acc);
    sx  = fmaf(x0, g0, sx);
    off_dt += 16384; off_g += 16384; off_x += 8192; off_bc += 768;
    float qdt = xz[off_dt], qg = xz[off_g], qx = bf2f(xconvb[off_x]);
    float qB = xp[off_bc + lane], qC = xp[off_bc + 64 + lane];
    dA = exp2f(dt1 * a2);
    state = fmaf(state, dA, (dt1 * x1) * B1);
    acc = fmaf(state * C1, g1, acc);
    sx  = fmaf(x1, g1, sx);
    dt0 = pdt; g0 = pg; x0 = px; B0 = pB; C0 = pC;
    dt1 = qdt; g1 = qg; x1 = qx; B1 = qB; C1 = qC;
  }
  state_out[((size_t)(b * DI + d)) * DS + lane] = state;
#pragma unroll
  for (int m = 32; m; m >>= 1) acc += __shfl_xor(acc, m, 64);
  if (lane == 0) accbuf[b * DI + d] = acc + Dv[d] * sx;
}

// ---------------- out = (acc/S) @ W_out^T + b_out ----------------
__global__ __launch_bounds__(256) void out_gemm_k(const float* __restrict__ accb,
                                                  const float* __restrict__ W_out,
                                                  const float* __restrict__ b_out,
                                                  float* __restrict__ outpre)
{
  int b = blockIdx.y;
  int m = blockIdx.x * 8 + (threadIdx.x >> 5);
  int dl = threadIdx.x & 31;
  const float* wr = W_out + (size_t)m * DI;
  const float* ac = accb + b * DI;
  float p = 0.f;
  for (int dd = dl; dd < DI; dd += 32) p = fmaf(wr[dd], ac[dd], p);
#pragma unroll
  for (int s = 16; s; s >>= 1) p += __shfl_xor(p, s, 32);
  if (dl == 0) outpre[b * DM + m] = p * (1.f / 2048.f) + b_out[m];
}

// ---------------- layernorm over d_model ----------------
__global__ __launch_bounds__(256) void ln_k(const float* __restrict__ outpre,
                                            const float* __restrict__ g,
                                            const float* __restrict__ bta,
                                            float* __restrict__ dout)
{
  int b = blockIdx.x;
  const float* row = outpre + b * DM;
  float s = 0.f, s2 = 0.f, vv[4];
#pragma unroll
  for (int i = 0; i < 4; i++) {
    float v = row[threadIdx.x + i * 256];
    vv[i] = v; s += v; s2 += v * v;
  }
#pragma unroll
  for (int m = 32; m; m >>= 1) { s += __shfl_xor(s, m, 64); s2 += __shfl_xor(s2, m, 64); }
  __shared__ float rs[4], rs2[4];
  int w = threadIdx.x >> 6;
  if ((threadIdx.x & 63) == 0) { rs[w] = s; rs2[w] = s2; }
  __syncthreads();
  float S = rs[0] + rs[1] + rs[2] + rs[3];
  float S2 = rs2[0] + rs2[1] + rs2[2] + rs2[3];
  float mu = S * (1.f / 1024.f);
  float var = S2 * (1.f / 1024.f) - mu * mu;
  float inv = rsqrtf(var + 1e-5f);
#pragma unroll
  for (int i = 0; i < 4; i++) {
    int c = threadIdx.x + i * 256;
    dout[b * DM + c] = (vv[i] - mu) * inv * g[c] + bta[c];
  }
}

extern "C" void kernel_launch(void* const* d_in, const int* in_sizes, int n_in,
                              void* d_out, int out_size, void* d_ws, size_t ws_size,
                              hipStream_t stream)
{
  const float* x      = (const float*)d_in[0];
  const float* state0 = (const float*)d_in[1];
  const float* W_in   = (const float*)d_in[2];
  const float* b_in   = (const float*)d_in[3];
  const float* conv_w = (const float*)d_in[4];
  const float* conv_b = (const float*)d_in[5];
  const float* W_xp   = (const float*)d_in[6];
  const float* b_xp   = (const float*)d_in[7];
  const float* W_dt   = (const float*)d_in[8];
  const float* b_dt   = (const float*)d_in[9];
  const float* A_log  = (const float*)d_in[10];
  const float* Dvec   = (const float*)d_in[11];
  const float* W_out  = (const float*)d_in[12];
  const float* b_out  = (const float*)d_in[13];
  const float* ln_g   = (const float*)d_in[14];
  const float* ln_b   = (const float*)d_in[15];
  float* out = (float*)d_out;   // [4*1024] out, then [4*2048*64] final_state

  char* ws = (char*)d_ws;
  unsigned short* xb     = (unsigned short*)(ws + 0);          // 16MB  x bf16
  unsigned short* wbin   = (unsigned short*)(ws + 16777216);   // 8MB   W_in bf16
  unsigned short* wbxp   = (unsigned short*)(ws + 25165824);   // 768KB W_xp bf16
  unsigned short* wbdt   = (unsigned short*)(ws + 25952256);   // 256KB W_dt bf16
  float*          xz     = (float*)(ws + 26214400);            // 128MB [8192][4096]: x_inner|gate, later dt|gate
  unsigned short* xcb    = (unsigned short*)(ws + 160432128);  // 32MB  x_conv bf16
  float*          xp     = (float*)(ws + 193986560);           // 6MB   [8192][192]
  unsigned short* xpb    = (unsigned short*)(ws + 200278016);  // 3MB   xp bf16
  float*          accb   = (float*)(ws + 203423744);           // 32KB  [4][2048]
  float*          outpre = (float*)(ws + 203456512);           // 16KB  [4][1024]

  cvt_bf16_k<<<8192, 256, 0, stream>>>(x,    xb,   8388608);
  cvt_bf16_k<<<4096, 256, 0, stream>>>(W_in, wbin, 4194304);
  cvt_bf16_k<<<384,  256, 0, stream>>>(W_xp, wbxp, 393216);
  cvt_bf16_k<<<128,  256, 0, stream>>>(W_dt, wbdt, 131072);
  // xz = x @ W_in^T + b_in; cols >= 2048 store silu(z) (the gate)
  gemm_bt<2,false><<<dim3(64,32), 256, 0, stream>>>(xb, wbin, xz, nullptr, b_in,
                                                    4096, 1024, 1024, 1024, 4096, 2048);
  conv_k<<<65536, 256, 0, stream>>>(xz, conv_w, conv_b, xcb);
  // xp = x_conv @ W_xp^T + b_xp  (also bf16 copy for dt GEMM)
  gemm_bt<0,true><<<dim3(64,2), 256, 0, stream>>>(xcb, wbxp, xp, xpb, b_xp,
                                                  192, 2048, 2048, 2048, 192, 0);
  // dt = softplus(dt_low @ W_dt^T + 2*b_dt), written into xz cols 0..2047
  gemm_bt<1,false><<<dim3(64,16), 256, 0, stream>>>(xpb, wbdt, xz, nullptr, b_dt,
                                                    2048, 64, 192, 64, 4096, 0);
  scan_k<<<2048, 256, 0, stream>>>(xz, xcb, xp, A_log, Dvec, state0, accb, out + 4096);
  out_gemm_k<<<dim3(128,4), 256, 0, stream>>>(accb, W_out, b_out, outpre);
  ln_k<<<4, 256, 0, stream>>>(outpre, ln_g, ln_b, out);
}